// Round 1
// 815.612 us; speedup vs baseline: 1.5390x; 1.5390x over previous
//
#include <hip/hip_runtime.h>
#include <hip/hip_bf16.h>

// Problem constants
#define B_   64
#define T_   32
#define S_   33      // T+1 LSTM steps
#define V_   32000
#define E_   512
#define H_   1024

typedef __attribute__((ext_vector_type(8))) short  bf16x8;
typedef __attribute__((ext_vector_type(4))) float  f32x4;

// Split fp32 into hi/lo bf16 pair: x ~= hi + lo  (error ~2^-16 rel)
__device__ inline void split2(float x, unsigned short& hi, unsigned short& lo) {
    __hip_bfloat16 h = __float2bfloat16(x);
    float r = x - __bfloat162float(h);
    __hip_bfloat16 l = __float2bfloat16(r);
    hi = *reinterpret_cast<unsigned short*>(&h);
    lo = *reinterpret_cast<unsigned short*>(&l);
}

// Load 8 contiguous fp32 and split into hi/lo bf16x8 fragments (fallback path).
__device__ inline void load_f32x8_hilo(const float* __restrict__ p,
                                       bf16x8& hi, bf16x8& lo) {
    const float4* q = reinterpret_cast<const float4*>(p);
    float4 v0 = q[0], v1 = q[1];
    float f[8] = {v0.x, v0.y, v0.z, v0.w, v1.x, v1.y, v1.z, v1.w};
#pragma unroll
    for (int j = 0; j < 8; ++j) {
        unsigned short h, l; split2(f[j], h, l);
        hi[j] = (short)h; lo[j] = (short)l;
    }
}

// ---------------------------------------------------------------------------
// Kernel 1: build X[t*64+b, e]  (time-major) as hi/lo bf16.
// t==0 -> features; t>=1 -> W_embed[:, captions[b,t-1]] + b_embed.
// grid 2112 blocks x 512 threads (thread = e).
// ---------------------------------------------------------------------------
__global__ __launch_bounds__(512) void build_x(
    const float* __restrict__ feat,   // [B,E]
    const int*   __restrict__ caps,   // [B,T] int32
    const float* __restrict__ Wemb,   // [E,V]
    const float* __restrict__ bemb,   // [E]
    unsigned short* __restrict__ Xhi,
    unsigned short* __restrict__ Xlo)
{
    int row = blockIdx.x;          // t*64 + b
    int t = row >> 6, b = row & 63;
    int e = threadIdx.x;
    float x;
    if (t == 0) {
        x = feat[b * E_ + e];
    } else {
        int cap = caps[b * T_ + (t - 1)];
        x = Wemb[(size_t)e * V_ + cap] + bemb[e];
    }
    unsigned short hi, lo; split2(x, hi, lo);
    Xhi[(size_t)row * E_ + e] = hi;
    Xlo[(size_t)row * E_ + e] = lo;
}

// ---------------------------------------------------------------------------
// Kernel 2: init LSTM state.  h -> hi/lo bf16, c fp32.
// ---------------------------------------------------------------------------
__global__ __launch_bounds__(256) void init_state(
    const float* __restrict__ h0,
    const float* __restrict__ c0,
    unsigned short* __restrict__ hhi,
    unsigned short* __restrict__ hlo,
    float* __restrict__ c)
{
    int idx = blockIdx.x * 256 + threadIdx.x;
    unsigned short hi, lo; split2(h0[idx], hi, lo);
    hhi[idx] = hi;
    hlo[idx] = lo;
    c[idx]   = c0[idx];
}

// ---------------------------------------------------------------------------
// Kernel 2b: pre-split a fp32 weight array into bf16 hi/lo (once; steps reuse 33x).
// ---------------------------------------------------------------------------
__global__ __launch_bounds__(256) void split_w(
    const float* __restrict__ src,
    unsigned short* __restrict__ hi,
    unsigned short* __restrict__ lo,
    int n4)   // element count / 4
{
    int idx = blockIdx.x * 256 + threadIdx.x;
    int stride = gridDim.x * 256;
    for (; idx < n4; idx += stride) {
        float4 v = reinterpret_cast<const float4*>(src)[idx];
        float f[4] = {v.x, v.y, v.z, v.w};
        unsigned short h[4], l[4];
#pragma unroll
        for (int j = 0; j < 4; ++j) split2(f[j], h[j], l[j]);
        ushort4 hv; hv.x = h[0]; hv.y = h[1]; hv.z = h[2]; hv.w = h[3];
        ushort4 lv; lv.x = l[0]; lv.y = l[1]; lv.z = l[2]; lv.w = l[3];
        *reinterpret_cast<ushort4*>(hi + (size_t)idx * 4) = hv;
        *reinterpret_cast<ushort4*>(lo + (size_t)idx * 4) = lv;
    }
}

// Kernel 2c: bsum = b_ih + b_hh  (4096 elems)
__global__ __launch_bounds__(256) void bias_sum(
    const float* __restrict__ a, const float* __restrict__ b,
    float* __restrict__ s)
{
    int i = blockIdx.x * 256 + threadIdx.x;
    s[i] = a[i] + b[i];
}

// ---------------------------------------------------------------------------
// Kernel 3 (x33): MFMA LSTM step, v2 — parallelism-first restructure.
//
// Output decomposition: block = (mgrp, jg):
//   mgrp in {0,1}: 32 batch rows (2 m-tiles of 16)
//   jg in [0,256): 4 h-columns x 4 gates = 16 gate-interleaved weight rows
//     lane lm -> nrow = (lm>>2)*1024 + jg*4 + (lm&3)
//   => the 16x16 output tile holds ALL 4 gates for 4 h-cols of 16 batches,
//      so the sigmoid/tanh/c-update is block-local (single fused kernel).
// Split-K over 6 waves: waves 0-1 = x-part (K=2x256), waves 2-5 = h-part
// (K=4x256); partials LDS-reduced. 3-term hi/lo MFMA math unchanged.
// Grid 512 x 384: 2 blocks/CU, 12 waves/CU (vs 4 before).
// bx = mgrp*256 + jg: same-W blocks are 256 apart -> same XCD -> L2 W-reuse.
// ---------------------------------------------------------------------------
template<bool PRESPLIT>
__global__ __launch_bounds__(384) void lstm_step(
    const unsigned short* __restrict__ Xhi,    // [2112, 512]
    const unsigned short* __restrict__ Xlo,
    const float* __restrict__ w_ih,            // [4096, 512]  (fallback)
    const float* __restrict__ w_hh,            // [4096, 1024] (fallback)
    const unsigned short* __restrict__ Wihhi,  // [4096, 512]  bf16 hi
    const unsigned short* __restrict__ Wihlo,
    const unsigned short* __restrict__ Whhhi,  // [4096, 1024] bf16 hi
    const unsigned short* __restrict__ Whhlo,
    const float* __restrict__ bsum,            // [4096] = b_ih + b_hh
    const unsigned short* __restrict__ hhi_in, // [64, 1024]
    const unsigned short* __restrict__ hlo_in,
    float* __restrict__ c,                     // [64, 1024]
    unsigned short* __restrict__ hhi_out,
    unsigned short* __restrict__ hlo_out,
    float* __restrict__ out,                   // [B][S][H] fp32
    int t)
{
    int bx   = blockIdx.x;
    int jg   = bx & 255;          // 4-col group within H
    int mgrp = bx >> 8;           // 0..1 : 32-batch group
    int wave = threadIdx.x >> 6;  // 0..5 : K-chunk
    int lane = threadIdx.x & 63;
    int lm   = lane & 15;
    int kq   = (lane >> 4) * 8;

    // gate-interleaved weight row for this lane (g = lm>>2, jj = lm&3)
    int nrow = (lm >> 2) * H_ + jg * 4 + (lm & 3);

    const unsigned short *Ahi, *Alo, *Bhi = nullptr, *Blo = nullptr;
    const float* Bf = nullptr;
    int lda, k0;
    if (wave < 2) {               // x-part, K = 512
        k0  = wave * 256;
        lda = E_;
        if (PRESPLIT) {
            Bhi = Wihhi + (size_t)nrow * E_;
            Blo = Wihlo + (size_t)nrow * E_;
        } else {
            Bf  = w_ih + (size_t)nrow * E_;
        }
        Ahi = Xhi + (size_t)(t * 64 + mgrp * 32) * E_;
        Alo = Xlo + (size_t)(t * 64 + mgrp * 32) * E_;
    } else {                      // h-part, K = 1024
        k0  = (wave - 2) * 256;
        lda = H_;
        if (PRESPLIT) {
            Bhi = Whhhi + (size_t)nrow * H_;
            Blo = Whhlo + (size_t)nrow * H_;
        } else {
            Bf  = w_hh + (size_t)nrow * H_;
        }
        Ahi = hhi_in + (size_t)(mgrp * 32) * H_;
        Alo = hlo_in + (size_t)(mgrp * 32) * H_;
    }

    f32x4 acc0 = f32x4{0.f, 0.f, 0.f, 0.f};   // m-tile 0 (rows lm)
    f32x4 acc1 = f32x4{0.f, 0.f, 0.f, 0.f};   // m-tile 1 (rows 16+lm)

#pragma unroll
    for (int kk = 0; kk < 256; kk += 32) {
        int k = k0 + kk + kq;
        bf16x8 bhi, blo;
        if constexpr (PRESPLIT) {
            bhi = *reinterpret_cast<const bf16x8*>(Bhi + k);
            blo = *reinterpret_cast<const bf16x8*>(Blo + k);
        } else {
            load_f32x8_hilo(Bf + k, bhi, blo);
        }
        bf16x8 a0h = *reinterpret_cast<const bf16x8*>(Ahi + (size_t)lm * lda + k);
        bf16x8 a0l = *reinterpret_cast<const bf16x8*>(Alo + (size_t)lm * lda + k);
        bf16x8 a1h = *reinterpret_cast<const bf16x8*>(Ahi + (size_t)(16 + lm) * lda + k);
        bf16x8 a1l = *reinterpret_cast<const bf16x8*>(Alo + (size_t)(16 + lm) * lda + k);
        acc0 = __builtin_amdgcn_mfma_f32_16x16x32_bf16(a0h, bhi, acc0, 0, 0, 0);
        acc0 = __builtin_amdgcn_mfma_f32_16x16x32_bf16(a0l, bhi, acc0, 0, 0, 0);
        acc0 = __builtin_amdgcn_mfma_f32_16x16x32_bf16(a0h, blo, acc0, 0, 0, 0);
        acc1 = __builtin_amdgcn_mfma_f32_16x16x32_bf16(a1h, bhi, acc1, 0, 0, 0);
        acc1 = __builtin_amdgcn_mfma_f32_16x16x32_bf16(a1l, bhi, acc1, 0, 0, 0);
        acc1 = __builtin_amdgcn_mfma_f32_16x16x32_bf16(a1h, blo, acc1, 0, 0, 0);
    }

    // partial tiles: [wave][mtile][row=batch_local][col=gate*4+jj] (+1 pad)
    __shared__ float pbuf[6][2][16][17];
    __shared__ float gbuf[2][16][17];
    int rbase = (lane >> 4) * 4;   // C/D: col=lane&15, row=(lane>>4)*4+r (verified)
#pragma unroll
    for (int r = 0; r < 4; ++r) {
        pbuf[wave][0][rbase + r][lm] = acc0[r];
        pbuf[wave][1][rbase + r][lm] = acc1[r];
    }
    __syncthreads();

    int tid = threadIdx.x;
    // reduce 6 K-partials + add bias: 512 values over 384 threads
    for (int idx = tid; idx < 512; idx += 384) {
        int mt = idx >> 8, rc = idx & 255;
        int row = rc >> 4, col = rc & 15;
        float v = pbuf[0][mt][row][col] + pbuf[1][mt][row][col]
                + pbuf[2][mt][row][col] + pbuf[3][mt][row][col]
                + pbuf[4][mt][row][col] + pbuf[5][mt][row][col];
        int n = (col >> 2) * H_ + jg * 4 + (col & 3);
        gbuf[mt][row][col] = v + bsum[n];
    }
    __syncthreads();

    // fused pointwise: 2 mtiles x 16 batches x 4 cols = 128 outputs
    if (tid < 128) {
        int mt = tid >> 6, bl = (tid >> 2) & 15, jj = tid & 3;
        int b = mgrp * 32 + mt * 16 + bl;
        int j = jg * 4 + jj;
        float iv = gbuf[mt][bl][ 0 + jj];
        float fv = gbuf[mt][bl][ 4 + jj];
        float gv = gbuf[mt][bl][ 8 + jj];
        float ov = gbuf[mt][bl][12 + jj];
        float si = 1.f / (1.f + expf(-iv));
        float sf = 1.f / (1.f + expf(-fv));
        float so = 1.f / (1.f + expf(-ov));
        float tg = tanhf(gv);
        size_t cidx = (size_t)b * H_ + j;
        float cn = sf * c[cidx] + si * tg;
        c[cidx] = cn;
        float hn = so * tanhf(cn);
        unsigned short hi, lo; split2(hn, hi, lo);
        hhi_out[cidx] = hi;
        hlo_out[cidx] = lo;
        out[((size_t)b * S_ + t) * H_ + j] = hn;   // fp32 write
    }
}

// ---------------------------------------------------------------------------
extern "C" void kernel_launch(void* const* d_in, const int* in_sizes, int n_in,
                              void* d_out, int out_size, void* d_ws, size_t ws_size,
                              hipStream_t stream)
{
    // Positional defaults (setup_inputs dict order)...
    const float* feat = (const float*)d_in[0];
    const int*   caps = (const int*)d_in[1];
    const float* Wemb = (const float*)d_in[2];
    const float* bemb = (const float*)d_in[3];
    const float* w_ih = (const float*)d_in[4];
    const float* w_hh = (const float*)d_in[5];
    const float* b_ih = (const float*)d_in[6];
    const float* b_hh = (const float*)d_in[7];
    const float* h0   = (const float*)d_in[8];
    const float* c0   = (const float*)d_in[9];
    // ...then override by unique element counts (r5-verified consistent).
    int nbias = 0, nstate = 0;
    for (int i = 0; i < n_in; ++i) {
        switch (in_sizes[i]) {
            case 64 * 512:        feat = (const float*)d_in[i]; break;
            case 64 * 32:         caps = (const int*)d_in[i];   break;
            case 512 * 32000:     Wemb = (const float*)d_in[i]; break;
            case 512:             bemb = (const float*)d_in[i]; break;
            case 4096 * 512:      w_ih = (const float*)d_in[i]; break;
            case 4096 * 1024:     w_hh = (const float*)d_in[i]; break;
            case 4096:
                if (nbias++ == 0) b_ih = (const float*)d_in[i];
                else              b_hh = (const float*)d_in[i];
                break;
            case 64 * 1024:
                if (nstate++ == 0) h0 = (const float*)d_in[i];
                else               c0 = (const float*)d_in[i];
                break;
            default: break;
        }
    }
    float* out = (float*)d_out;   // fp32 output (r8-verified)

    // workspace layout: base (~4.9 MB, r8-verified) + bsum + presplit W (25.2 MB)
    char* ws = (char*)d_ws;
    unsigned short* Xhi  = (unsigned short*)ws; ws += (size_t)2112 * 512 * 2;
    unsigned short* Xlo  = (unsigned short*)ws; ws += (size_t)2112 * 512 * 2;
    unsigned short* hhiA = (unsigned short*)ws; ws += (size_t)B_ * H_ * 2;
    unsigned short* hloA = (unsigned short*)ws; ws += (size_t)B_ * H_ * 2;
    unsigned short* hhiB = (unsigned short*)ws; ws += (size_t)B_ * H_ * 2;
    unsigned short* hloB = (unsigned short*)ws; ws += (size_t)B_ * H_ * 2;
    float* cbuf          = (float*)ws;          ws += (size_t)B_ * H_ * 4;
    float* bsum          = (float*)ws;          ws += (size_t)4096 * 4;
    unsigned short* Wihhi = (unsigned short*)ws; ws += (size_t)4096 * 512 * 2;
    unsigned short* Wihlo = (unsigned short*)ws; ws += (size_t)4096 * 512 * 2;
    unsigned short* Whhhi = (unsigned short*)ws; ws += (size_t)4096 * 1024 * 2;
    unsigned short* Whhlo = (unsigned short*)ws; ws += (size_t)4096 * 1024 * 2;
    size_t needed = (size_t)(ws - (char*)d_ws);
    bool presplit = ws_size >= needed;   // host-side decision, no sync

    build_x<<<2112, 512, 0, stream>>>(feat, caps, Wemb, bemb, Xhi, Xlo);
    init_state<<<256, 256, 0, stream>>>(h0, c0, hhiA, hloA, cbuf);
    bias_sum<<<16, 256, 0, stream>>>(b_ih, b_hh, bsum);
    if (presplit) {
        split_w<<<2048, 256, 0, stream>>>(w_ih, Wihhi, Wihlo, (4096 * 512) / 4);
        split_w<<<2048, 256, 0, stream>>>(w_hh, Whhhi, Whhlo, (4096 * 1024) / 4);
    }

    for (int t = 0; t < S_; ++t) {
        const unsigned short* hhi_in = (t & 1) ? hhiB : hhiA;
        const unsigned short* hlo_in = (t & 1) ? hloB : hloA;
        unsigned short* hhi_out = (t & 1) ? hhiA : hhiB;
        unsigned short* hlo_out = (t & 1) ? hloA : hloB;
        if (presplit) {
            lstm_step<true><<<512, 384, 0, stream>>>(
                Xhi, Xlo, w_ih, w_hh, Wihhi, Wihlo, Whhhi, Whhlo, bsum,
                hhi_in, hlo_in, cbuf, hhi_out, hlo_out, out, t);
        } else {
            lstm_step<false><<<512, 384, 0, stream>>>(
                Xhi, Xlo, w_ih, w_hh, Wihhi, Wihlo, Whhhi, Whhlo, bsum,
                hhi_in, hlo_in, cbuf, hhi_out, hlo_out, out, t);
        }
    }
}